// Round 2
// baseline (363.890 us; speedup 1.0000x reference)
//
#include <hip/hip_runtime.h>

#define NB 16
#define NT 4096
#define ND 512
#define NLEV 12
#define UPSTRIDE 4104  // T+1=4097 padded to multiple of 8

// ---------------- Kernel A: next(j) = first i>j with ||x_j - x_i|| > 32 ----------------
// One wave (64 lanes) per j. Lane owns 8 floats (two float4 slots: lane and lane+64).
// Squared distance: f32 diffs (matches reference), squares summed exactly in f64,
// then rounded to f32 and passed through sqrtf > 32.0f to mimic the reference pipeline.
__global__ __launch_bounds__(256) void kA_next(const float* __restrict__ in,
                                               int* __restrict__ nxt) {
    int lin  = blockIdx.x * 4 + (threadIdx.x >> 6);   // linear (b, j)
    int lane = threadIdx.x & 63;
    int b = lin >> 12;          // / NT
    int j = lin & (NT - 1);
    const float* base = in + (size_t)b * NT * ND;
    const float4* repp = (const float4*)(base + (size_t)j * ND);
    float4 r0 = repp[lane];
    float4 r1 = repp[lane + 64];
    int i = j + 1;
    for (; i < NT; ++i) {
        const float4* fp = (const float4*)(base + (size_t)i * ND);
        float4 x0 = fp[lane];
        float4 x1 = fp[lane + 64];
        float d0 = r0.x - x0.x, d1 = r0.y - x0.y, d2 = r0.z - x0.z, d3 = r0.w - x0.w;
        float d4 = r1.x - x1.x, d5 = r1.y - x1.y, d6 = r1.z - x1.z, d7 = r1.w - x1.w;
        double s = (double)d0 * d0 + (double)d1 * d1 + (double)d2 * d2 + (double)d3 * d3
                 + (double)d4 * d4 + (double)d5 * d5 + (double)d6 * d6 + (double)d7 * d7;
        #pragma unroll
        for (int off = 32; off >= 1; off >>= 1) s += __shfl_xor(s, off, 64);
        float sf = (float)s;                 // correctly-rounded f32 of exact sum
        if (sqrtf(sf) > 32.0f) break;        // mimic reference: f32 norm > cutoff
    }
    if (lane == 0) nxt[b * NT + j] = i;      // i == NT if never exceeded
}

// ---------------- Kernel B: binary-lifting tables up[k][j] = f^(2^k)(j) --------------
// One block per batch element; tables built in LDS (ushort), each level flushed to global.
__global__ __launch_bounds__(256) void kB_build(const int* __restrict__ nxt,
                                                unsigned short* __restrict__ up) {
    __shared__ unsigned short cur[NT + 8];
    __shared__ unsigned short nx[NT + 8];
    int b = blockIdx.x;
    int t = threadIdx.x;
    for (int j = t; j <= NT; j += 256)
        cur[j] = (j < NT) ? (unsigned short)nxt[b * NT + j] : (unsigned short)NT;
    __syncthreads();
    {
        unsigned short* d0 = up + (size_t)(0 * NB + b) * UPSTRIDE;
        for (int j = t; j <= NT; j += 256) d0[j] = cur[j];
    }
    for (int k = 1; k < NLEV; ++k) {
        for (int j = t; j <= NT; j += 256) nx[j] = cur[cur[j]];
        __syncthreads();
        for (int j = t; j <= NT; j += 256) cur[j] = nx[j];
        __syncthreads();
        unsigned short* dk = up + (size_t)(k * NB + b) * UPSTRIDE;
        for (int j = t; j <= NT; j += 256) dk[j] = cur[j];
    }
}

// ---------------- Kernel C: per-frame descend from node 0 ---------------------------
// pos = largest segment-start <= i, cnt = its rank. Starts emit startlist[rank]=i.
__global__ __launch_bounds__(256) void kC_descend(const unsigned short* __restrict__ up,
                                                  int* __restrict__ start,
                                                  int* __restrict__ nseg,
                                                  float* __restrict__ out_tail) {
    int idx = blockIdx.x * 256 + threadIdx.x;
    int b = idx >> 12;
    int i = idx & (NT - 1);
    int pos = 0, cnt = 0;
    #pragma unroll
    for (int k = NLEV - 1; k >= 0; --k) {
        int t = up[(size_t)(k * NB + b) * UPSTRIDE + pos];
        if (t <= i) { pos = t; cnt += (1 << k); }
    }
    if (pos == i) start[b * NT + cnt] = i;
    if (i == NT - 1) {
        nseg[b] = cnt + 1;
        out_tail[b] = (float)(cnt + 1);   // n_segs output (float-encoded)
    }
}

// ---------------- Kernel D: segment means + zero padding ----------------------------
// One block (128 threads x float4 = 512 cols) per output row.
__global__ __launch_bounds__(128) void kD_means(const float* __restrict__ in,
                                                const int* __restrict__ nxt,
                                                const int* __restrict__ start,
                                                const int* __restrict__ nseg,
                                                float* __restrict__ out) {
    int r = blockIdx.x & (NT - 1);
    int b = blockIdx.x >> 12;
    int t = threadIdx.x;
    float4 acc = make_float4(0.f, 0.f, 0.f, 0.f);
    int n = nseg[b];
    if (r < n) {
        int s = start[b * NT + r];
        int e = nxt[b * NT + s];
        const float4* base = (const float4*)(in + (size_t)(b * NT + s) * ND);
        int cnt = e - s;
        for (int f = 0; f < cnt; ++f) {
            float4 v = base[(size_t)f * (ND / 4) + t];
            acc.x += v.x; acc.y += v.y; acc.z += v.z; acc.w += v.w;
        }
        float c = (float)cnt;
        acc.x /= c; acc.y /= c; acc.z /= c; acc.w /= c;
    }
    ((float4*)out)[(size_t)(b * NT + r) * (ND / 4) + t] = acc;
}

extern "C" void kernel_launch(void* const* d_in, const int* in_sizes, int n_in,
                              void* d_out, int out_size, void* d_ws, size_t ws_size,
                              hipStream_t stream) {
    const float* in = (const float*)d_in[0];
    float* out = (float*)d_out;
    char* ws = (char*)d_ws;

    int*            nxt   = (int*)(ws + 0);                    // 16*4096*4   = 256 KiB
    int*            start = (int*)(ws + 262144);               // 256 KiB
    int*            nseg  = (int*)(ws + 524288);               // 64 B
    unsigned short* up    = (unsigned short*)(ws + 524352);    // 12*16*4104*2 ≈ 1.5 MiB

    kA_next   <<<NB * NT / 4,  256, 0, stream>>>(in, nxt);
    kB_build  <<<NB,           256, 0, stream>>>(nxt, up);
    kC_descend<<<NB * NT / 256,256, 0, stream>>>(up, start, nseg,
                                                 out + (size_t)NB * NT * ND);
    kD_means  <<<NB * NT,      128, 0, stream>>>(in, nxt, start, nseg, out);
}

// Round 3
// 334.729 us; speedup vs baseline: 1.0871x; 1.0871x over previous
//
#include <hip/hip_runtime.h>

#define NB 16
#define NT 4096
#define ND 512
#define NLEV 12
#define UPSTRIDE 4104  // T+1=4097 padded to multiple of 8

// f32 distance^2 accumulate: 8 elements per lane (two float4s)
#define DIST8_F32(sout, y0, y1)                                   \
    {                                                             \
        float d_;                                                 \
        d_ = r0.x - (y0).x; sout = d_ * d_;                       \
        d_ = r0.y - (y0).y; sout = fmaf(d_, d_, sout);            \
        d_ = r0.z - (y0).z; sout = fmaf(d_, d_, sout);            \
        d_ = r0.w - (y0).w; sout = fmaf(d_, d_, sout);            \
        d_ = r1.x - (y1).x; sout = fmaf(d_, d_, sout);            \
        d_ = r1.y - (y1).y; sout = fmaf(d_, d_, sout);            \
        d_ = r1.z - (y1).z; sout = fmaf(d_, d_, sout);            \
        d_ = r1.w - (y1).w; sout = fmaf(d_, d_, sout);            \
    }

// Exact path: f32 diffs, squares summed exactly in f64, rounded once to f32,
// compared against 1024.0f (== (32^2), monotone-equivalent to sqrtf(s)>32.0f).
__device__ __forceinline__ bool decide_exact(const float* __restrict__ base, int row,
                                             int lane, float4 r0, float4 r1) {
    const float4* fp = (const float4*)(base + (size_t)row * ND);
    float4 y0 = fp[lane];
    float4 y1 = fp[lane + 64];
    float d;
    double sd;
    d = r0.x - y0.x; sd  = (double)d * d;
    d = r0.y - y0.y; sd += (double)d * d;
    d = r0.z - y0.z; sd += (double)d * d;
    d = r0.w - y0.w; sd += (double)d * d;
    d = r1.x - y1.x; sd += (double)d * d;
    d = r1.y - y1.y; sd += (double)d * d;
    d = r1.z - y1.z; sd += (double)d * d;
    d = r1.w - y1.w; sd += (double)d * d;
    #pragma unroll
    for (int off = 32; off >= 1; off >>= 1) sd += __shfl_xor(sd, off, 64);
    return ((float)sd > 1024.0f);
}

// Screen with +-0.25 margin around 1024; ambiguous (rare, wave-uniform) -> exact.
__device__ __forceinline__ bool screen1(float sk, const float* __restrict__ base,
                                        int row, int lane, float4 r0, float4 r1) {
    if (sk > 1024.25f) return true;
    if (sk < 1023.75f) return false;
    return decide_exact(base, row, lane, r0, r1);
}

// ---------------- Kernel A: next(j) via 4-way speculative probing ----------------
__global__ __launch_bounds__(256) void kA_next(const float* __restrict__ in,
                                               int* __restrict__ nxt) {
    int lin  = blockIdx.x * 4 + (threadIdx.x >> 6);
    int lane = threadIdx.x & 63;
    int b = lin >> 12;
    int j = lin & (NT - 1);
    const float* base = in + (size_t)b * NT * ND;
    const float4* repp = (const float4*)(base + (size_t)j * ND);
    float4 r0 = repp[lane];
    float4 r1 = repp[lane + 64];

    int result = NT;
    int i = j + 1;
    while (i < NT) {
        int row0 = i;
        int row1 = (i + 1 < NT) ? i + 1 : NT - 1;
        int row2 = (i + 2 < NT) ? i + 2 : NT - 1;
        int row3 = (i + 3 < NT) ? i + 3 : NT - 1;
        const float4* f0 = (const float4*)(base + (size_t)row0 * ND);
        const float4* f1 = (const float4*)(base + (size_t)row1 * ND);
        const float4* f2 = (const float4*)(base + (size_t)row2 * ND);
        const float4* f3 = (const float4*)(base + (size_t)row3 * ND);
        float4 a0 = f0[lane], b0 = f0[lane + 64];
        float4 a1 = f1[lane], b1 = f1[lane + 64];
        float4 a2 = f2[lane], b2 = f2[lane + 64];
        float4 a3 = f3[lane], b3 = f3[lane + 64];

        float s0, s1, s2, s3;
        DIST8_F32(s0, a0, b0);
        DIST8_F32(s1, a1, b1);
        DIST8_F32(s2, a2, b2);
        DIST8_F32(s3, a3, b3);

        #pragma unroll
        for (int off = 32; off >= 1; off >>= 1) {
            s0 += __shfl_xor(s0, off, 64);
            s1 += __shfl_xor(s1, off, 64);
            s2 += __shfl_xor(s2, off, 64);
            s3 += __shfl_xor(s3, off, 64);
        }

        int nv = NT - i;  // candidates valid this batch (>=1)
        int found = -1;
        if (screen1(s0, base, row0, lane, r0, r1)) found = i;
        else if (nv > 1 && screen1(s1, base, row1, lane, r0, r1)) found = i + 1;
        else if (nv > 2 && screen1(s2, base, row2, lane, r0, r1)) found = i + 2;
        else if (nv > 3 && screen1(s3, base, row3, lane, r0, r1)) found = i + 3;
        if (found >= 0) { result = found; break; }
        i += 4;
    }
    if (lane == 0) nxt[b * NT + j] = result;
}

// ---------------- Kernel B: binary-lifting tables up[k][j] = f^(2^k)(j) ----------
__global__ __launch_bounds__(1024) void kB_build(const int* __restrict__ nxt,
                                                 unsigned short* __restrict__ up) {
    __shared__ unsigned short cur[NT + 8];
    __shared__ unsigned short nx[NT + 8];
    int b = blockIdx.x;
    int t = threadIdx.x;
    for (int j = t; j <= NT; j += 1024)
        cur[j] = (j < NT) ? (unsigned short)nxt[b * NT + j] : (unsigned short)NT;
    __syncthreads();
    {
        unsigned short* d0 = up + (size_t)(0 * NB + b) * UPSTRIDE;
        for (int j = t; j <= NT; j += 1024) d0[j] = cur[j];
    }
    for (int k = 1; k < NLEV; ++k) {
        for (int j = t; j <= NT; j += 1024) nx[j] = cur[cur[j]];
        __syncthreads();
        for (int j = t; j <= NT; j += 1024) cur[j] = nx[j];
        __syncthreads();
        unsigned short* dk = up + (size_t)(k * NB + b) * UPSTRIDE;
        for (int j = t; j <= NT; j += 1024) dk[j] = cur[j];
    }
}

// ---------------- Kernel C: per-frame descend from node 0 ------------------------
__global__ __launch_bounds__(256) void kC_descend(const unsigned short* __restrict__ up,
                                                  int* __restrict__ start,
                                                  int* __restrict__ nseg,
                                                  float* __restrict__ out_tail) {
    int idx = blockIdx.x * 256 + threadIdx.x;
    int b = idx >> 12;
    int i = idx & (NT - 1);
    int pos = 0, cnt = 0;
    #pragma unroll
    for (int k = NLEV - 1; k >= 0; --k) {
        int t = up[(size_t)(k * NB + b) * UPSTRIDE + pos];
        if (t <= i) { pos = t; cnt += (1 << k); }
    }
    if (pos == i) start[b * NT + cnt] = i;
    if (i == NT - 1) {
        nseg[b] = cnt + 1;
        out_tail[b] = (float)(cnt + 1);   // n_segs output (float-encoded)
    }
}

// ---------------- Kernel D: segment means, one wave per row, 8 rows/wave ---------
__global__ __launch_bounds__(256) void kD_means(const float* __restrict__ in,
                                                const int* __restrict__ nxt,
                                                const int* __restrict__ start,
                                                const int* __restrict__ nseg,
                                                float* __restrict__ out) {
    int wid  = threadIdx.x >> 6;
    int lane = threadIdx.x & 63;
    int g = blockIdx.x * 4 + wid;       // 0..8191
    int L0 = g * 8;
    for (int L = L0; L < L0 + 8; ++L) {
        int b = L >> 12;
        int r = L & (NT - 1);
        float4 acc0 = make_float4(0.f, 0.f, 0.f, 0.f);
        float4 acc1 = make_float4(0.f, 0.f, 0.f, 0.f);
        int n = nseg[b];
        if (r < n) {
            int s = start[b * NT + r];
            int e = nxt[b * NT + s];
            const float4* base = (const float4*)(in + (size_t)(b * NT + s) * ND);
            int cnt = e - s;
            for (int f = 0; f < cnt; ++f) {
                float4 v0 = base[(size_t)f * (ND / 4) + lane];
                float4 v1 = base[(size_t)f * (ND / 4) + lane + 64];
                acc0.x += v0.x; acc0.y += v0.y; acc0.z += v0.z; acc0.w += v0.w;
                acc1.x += v1.x; acc1.y += v1.y; acc1.z += v1.z; acc1.w += v1.w;
            }
            float c = (float)cnt;
            acc0.x /= c; acc0.y /= c; acc0.z /= c; acc0.w /= c;
            acc1.x /= c; acc1.y /= c; acc1.z /= c; acc1.w /= c;
        }
        float4* orow = (float4*)(out + (size_t)(b * NT + r) * ND);
        orow[lane]      = acc0;
        orow[lane + 64] = acc1;
    }
}

extern "C" void kernel_launch(void* const* d_in, const int* in_sizes, int n_in,
                              void* d_out, int out_size, void* d_ws, size_t ws_size,
                              hipStream_t stream) {
    const float* in = (const float*)d_in[0];
    float* out = (float*)d_out;
    char* ws = (char*)d_ws;

    int*            nxt   = (int*)(ws + 0);                    // 256 KiB
    int*            start = (int*)(ws + 262144);               // 256 KiB
    int*            nseg  = (int*)(ws + 524288);               // 64 B
    unsigned short* up    = (unsigned short*)(ws + 524352);    // ~1.5 MiB

    kA_next   <<<NB * NT / 4,   256,  0, stream>>>(in, nxt);
    kB_build  <<<NB,            1024, 0, stream>>>(nxt, up);
    kC_descend<<<NB * NT / 256, 256,  0, stream>>>(up, start, nseg,
                                                   out + (size_t)NB * NT * ND);
    kD_means  <<<2048,          256,  0, stream>>>(in, nxt, start, nseg, out);
}